// Round 1
// baseline (961.389 us; speedup 1.0000x reference)
//
#include <hip/hip_runtime.h>
#include <cmath>

#define BB 8192
#define LL 200
#define DD 64

__global__ __launch_bounds__(256, 2)
void din_fused_kernel(const int* __restrict__ item_seq,    // (B,L)
                      const int* __restrict__ seq_len_p,   // (B,1)
                      const int* __restrict__ tgt_item,    // (B,1)
                      const float* __restrict__ ctx_feat,  // (B,9)
                      const float* __restrict__ emb,       // (100001,64)
                      const float* __restrict__ aw1, const float* __restrict__ ab1,
                      const float* __restrict__ aw2, const float* __restrict__ ab2,
                      const float* __restrict__ aw3, const float* __restrict__ ab3,
                      const float* __restrict__ cw,  const float* __restrict__ cb,
                      const float* __restrict__ mw1, const float* __restrict__ mb1,
                      const float* __restrict__ mw2, const float* __restrict__ mb2,
                      const float* __restrict__ mw3, const float* __restrict__ mb3,
                      float* __restrict__ out)
{
    const int b = blockIdx.x;
    const int t = threadIdx.x;
    const int lane_j = t & 63;   // 0..63 (column for h1)
    const int grp    = t >> 6;   // wave id 0..3
    const int j2     = t & 31;   // column for h2/scores

    __shared__ float s_seq[LL * DD];     // 51200 B, fp32 seq embeddings
    __shared__ float s_scores[LL];       // attention scores -> exp values
    __shared__ float s_h1[8 * 64];       // h1 chunk buffer
    __shared__ float s_h2[8 * 32];       // h2 chunk buffer
    __shared__ float s_qc[64];           // target-half of aw1 matvec (+ab1)
    __shared__ float s_comb[160];        // [attended(64) | tgt(64) | ctx(32)]
    __shared__ float s_part[4 * 64];     // attended partial sums
    __shared__ int   s_items[LL];
    __shared__ float s_red[1];           // 1/sum(exp)
    __shared__ float s_hm1[128];         // final-MLP hidden 1
    __shared__ float s_ctxf[9];

    const int tgt = tgt_item[b];
    const int len = seq_len_p[b];

    if (t < LL)               s_items[t]  = item_seq[b * LL + t];
    if (t >= 64 && t < 128)   s_comb[t]   = emb[tgt * DD + (t - 64)];
    if (t < 9)                s_ctxf[t]   = ctx_feat[b * 9 + t];
    __syncthreads();

    // ---- gather sequence embeddings into LDS (float4, coalesced rows) ----
    {
        const float4* embv = (const float4*)emb;
        float4* seqv = (float4*)s_seq;
        for (int idx = t; idx < LL * 16; idx += 256) {
            int l = idx >> 4, c = idx & 15;
            seqv[l * 16 + c] = embv[s_items[l] * 16 + c];
        }
    }

    // ---- qc[j] = ab1[j] + tgt . aw1[0:64, j]  (target-half, once per block)
    if (t < 64) {
        float acc0 = ab1[t], acc1 = 0.f;
        for (int d = 0; d < 64; d += 2) {
            acc0 += s_comb[64 + d]     * aw1[d * 64 + t];
            acc1 += s_comb[64 + d + 1] * aw1[(d + 1) * 64 + t];
        }
        s_qc[t] = acc0 + acc1;
    }
    // ---- ctx hidden: relu(cf @ cw + cb) -> comb[128..159]
    if (t >= 64 && t < 96) {
        int j = t - 64;
        float acc = cb[j];
        for (int k = 0; k < 9; ++k) acc += s_ctxf[k] * cw[k * 32 + j];
        s_comb[128 + j] = fmaxf(acc, 0.f);
    }

    // ---- preload attention-MLP weight columns into registers ----
    float wA[64];   // aw1[64+d][lane_j]  (sequence half)
    #pragma unroll
    for (int d = 0; d < 64; ++d) wA[d] = aw1[(64 + d) * 64 + lane_j];
    float wB[64];   // aw2[d][j2]
    #pragma unroll
    for (int d = 0; d < 64; ++d) wB[d] = aw2[d * 32 + j2];
    const float w3    = aw3[j2];
    const float bias2 = ab2[j2];
    const float b3    = ab3[0];
    __syncthreads();
    const float qc_j = s_qc[lane_j];

    // ---- attention MLP over all 200 positions, chunks of 8 ----
    for (int c0 = 0; c0 < LL; c0 += 8) {
        // h1: each thread does 2 positions, column lane_j
        {
            const int l0 = c0 + grp * 2;
            const float4* s0 = (const float4*)&s_seq[l0 * 64];
            const float4* s1 = (const float4*)&s_seq[(l0 + 1) * 64];
            float a0 = qc_j, a0b = 0.f, a1 = qc_j, a1b = 0.f;
            #pragma unroll
            for (int dq = 0; dq < 16; ++dq) {
                float4 e0 = s0[dq];
                float4 e1 = s1[dq];
                a0  += e0.x * wA[dq*4+0] + e0.y * wA[dq*4+1];
                a0b += e0.z * wA[dq*4+2] + e0.w * wA[dq*4+3];
                a1  += e1.x * wA[dq*4+0] + e1.y * wA[dq*4+1];
                a1b += e1.z * wA[dq*4+2] + e1.w * wA[dq*4+3];
            }
            s_h1[(grp * 2)     * 64 + lane_j] = fmaxf(a0 + a0b, 0.f);
            s_h1[(grp * 2 + 1) * 64 + lane_j] = fmaxf(a1 + a1b, 0.f);
        }
        __syncthreads();
        // h2: 8 positions x 32 columns = 256 outputs
        {
            const int lg = t >> 5;
            const float4* h1v = (const float4*)&s_h1[lg * 64];
            float acc0 = bias2, acc1 = 0.f;
            #pragma unroll
            for (int dq = 0; dq < 16; ++dq) {
                float4 h = h1v[dq];
                acc0 += h.x * wB[dq*4+0] + h.y * wB[dq*4+1];
                acc1 += h.z * wB[dq*4+2] + h.w * wB[dq*4+3];
            }
            s_h2[lg * 32 + j2] = fmaxf(acc0 + acc1, 0.f);
        }
        __syncthreads();
        // scores: 8 positions, dot-32 + shuffle reduce within 32-lane groups
        {
            const int lg = t >> 5;
            float p = s_h2[lg * 32 + j2] * w3;
            p += __shfl_down(p, 16, 32);
            p += __shfl_down(p, 8, 32);
            p += __shfl_down(p, 4, 32);
            p += __shfl_down(p, 2, 32);
            p += __shfl_down(p, 1, 32);
            if (j2 == 0) s_scores[c0 + lg] = p + b3;
        }
        __syncthreads();
    }

    // ---- masked softmax over l < len (wave 0 only) ----
    if (t < 64) {
        float m = -1e30f;
        for (int l = t; l < len; l += 64) m = fmaxf(m, s_scores[l]);
        #pragma unroll
        for (int off = 32; off; off >>= 1) m = fmaxf(m, __shfl_xor(m, off, 64));
        float e = 0.f;
        for (int l = t; l < len; l += 64) {
            float v = expf(s_scores[l] - m);
            s_scores[l] = v;
            e += v;
        }
        #pragma unroll
        for (int off = 32; off; off >>= 1) e += __shfl_xor(e, off, 64);
        if (t == 0) s_red[0] = 1.f / e;
    }
    __syncthreads();

    // ---- attended[d] = sum_l w[l] * seq[l][d] ----
    {
        const float inv = s_red[0];
        float acc = 0.f;
        for (int l = grp; l < len; l += 4)
            acc += s_scores[l] * s_seq[l * 64 + lane_j];
        s_part[grp * 64 + lane_j] = acc * inv;
    }
    __syncthreads();
    if (t < 64)
        s_comb[t] = (s_part[t] + s_part[64 + t]) + (s_part[128 + t] + s_part[192 + t]);
    __syncthreads();

    // ---- final MLP: 160 -> 128 -> 64 -> 1, sigmoid ----
    if (t < 128) {
        float acc0 = 0.f, acc1 = 0.f;
        #pragma unroll 4
        for (int k = 0; k < 160; k += 2) {
            acc0 += s_comb[k]     * mw1[k * 128 + t];
            acc1 += s_comb[k + 1] * mw1[(k + 1) * 128 + t];
        }
        s_hm1[t] = fmaxf(acc0 + acc1 + mb1[t], 0.f);
    }
    __syncthreads();
    if (t < 64) {
        float acc0 = 0.f, acc1 = 0.f;
        #pragma unroll 4
        for (int k = 0; k < 128; k += 2) {
            acc0 += s_hm1[k]     * mw2[k * 64 + t];
            acc1 += s_hm1[k + 1] * mw2[(k + 1) * 64 + t];
        }
        float h = fmaxf(acc0 + acc1 + mb2[t], 0.f);
        float p = h * mw3[t];
        #pragma unroll
        for (int off = 32; off; off >>= 1) p += __shfl_xor(p, off, 64);
        if (t == 0) out[b] = 1.f / (1.f + expf(-(p + mb3[0])));
    }
}

extern "C" void kernel_launch(void* const* d_in, const int* in_sizes, int n_in,
                              void* d_out, int out_size, void* d_ws, size_t ws_size,
                              hipStream_t stream)
{
    const int*   item_seq  = (const int*)  d_in[0];
    // d_in[1] click_sequence: unused by the reference
    const int*   seq_len   = (const int*)  d_in[2];
    const int*   tgt_item  = (const int*)  d_in[3];
    const float* ctx_feat  = (const float*)d_in[4];
    const float* emb       = (const float*)d_in[5];
    const float* aw1 = (const float*)d_in[6];
    const float* ab1 = (const float*)d_in[7];
    const float* aw2 = (const float*)d_in[8];
    const float* ab2 = (const float*)d_in[9];
    const float* aw3 = (const float*)d_in[10];
    const float* ab3 = (const float*)d_in[11];
    const float* cw  = (const float*)d_in[12];
    const float* cb  = (const float*)d_in[13];
    const float* mw1 = (const float*)d_in[14];
    const float* mb1 = (const float*)d_in[15];
    const float* mw2 = (const float*)d_in[16];
    const float* mb2 = (const float*)d_in[17];
    const float* mw3 = (const float*)d_in[18];
    const float* mb3 = (const float*)d_in[19];
    float* out = (float*)d_out;

    hipLaunchKernelGGL(din_fused_kernel, dim3(BB), dim3(256), 0, stream,
                       item_seq, seq_len, tgt_item, ctx_feat, emb,
                       aw1, ab1, aw2, ab2, aw3, ab3, cw, cb,
                       mw1, mb1, mw2, mb2, mw3, mb3, out);
}

// Round 2
// 398.605 us; speedup vs baseline: 2.4119x; 2.4119x over previous
//
#include <hip/hip_runtime.h>
#include <cmath>

#define BB 8192
#define LL 200

typedef __attribute__((ext_vector_type(8))) short s16x8;   // 8 bf16 = 4 VGPRs (MFMA A/B frag)
typedef __attribute__((ext_vector_type(4))) short s16x4;
typedef __attribute__((ext_vector_type(4))) float f32x4;   // MFMA C/D frag

__device__ __forceinline__ short f2bf(float f) {
    union { float f; unsigned u; } v; v.f = f;
    unsigned r = v.u + 0x7FFFu + ((v.u >> 16) & 1u);   // RNE
    return (short)(r >> 16);
}
__device__ __forceinline__ float bf2f(short s) {
    union { unsigned u; float f; } v; v.u = ((unsigned)(unsigned short)s) << 16;
    return v.f;
}

// LDS row strides: 72 bf16 = 144 B (=36 dwords) -> row r hits bank r*4 mod 32:
// 16 rows spread over 8 bank-groups, 2-way aliasing = free (m136). 144 % 16 == 0
// keeps ds_read_b128 16-B alignment. Pad cols 64..71 are never read by MFMA frags.
#define SEQ_PITCH 72

__global__ __launch_bounds__(256, 2)
void din_fused_kernel(const int* __restrict__ item_seq,
                      const int* __restrict__ seq_len_p,
                      const int* __restrict__ tgt_item,
                      const float* __restrict__ ctx_feat,
                      const float* __restrict__ emb,
                      const float* __restrict__ aw1, const float* __restrict__ ab1,
                      const float* __restrict__ aw2, const float* __restrict__ ab2,
                      const float* __restrict__ aw3, const float* __restrict__ ab3,
                      const float* __restrict__ cw,  const float* __restrict__ cb,
                      const float* __restrict__ mw1, const float* __restrict__ mb1,
                      const float* __restrict__ mw2, const float* __restrict__ mb2,
                      const float* __restrict__ mw3, const float* __restrict__ mb3,
                      float* __restrict__ out)
{
    const int b    = blockIdx.x;
    const int t    = threadIdx.x;
    const int lane = t & 63;
    const int wave = t >> 6;
    const int quad = lane >> 4;   // 0..3
    const int r16  = lane & 15;   // 0..15

    __shared__ short s_seq[208 * SEQ_PITCH];      // 29,952 B  bf16 seq embeddings
    __shared__ short s_h1[4 * 16 * SEQ_PITCH];    //  9,216 B  per-wave H1 chunk
    __shared__ short s_w1T[64 * SEQ_PITCH];       //  9,216 B  aw1 seq-half, transposed [n][k]
    __shared__ short s_w2T[32 * SEQ_PITCH];       //  4,608 B  aw2 transposed [n][k]
    __shared__ float s_scores[208];
    __shared__ int   s_items[200];
    __shared__ float s_comb[160];                 // [attended | tgt | ctx]
    __shared__ float s_part[256];
    __shared__ float s_qc[64];
    __shared__ float s_hm1[128];
    __shared__ float s_red;

    const int tgt = tgt_item[b];
    const int len = seq_len_p[b];

    if (t < 200)             s_items[t] = item_seq[b * 200 + t];
    if (t >= 64 && t < 128)  s_comb[t]  = emb[tgt * 64 + (t - 64)];
    __syncthreads();   // A

    // ---- gather seq embeddings -> LDS bf16 (only rows < len are ever read) ----
    {
        const float4* embv = (const float4*)emb;
        for (int idx = t; idx < 200 * 16; idx += 256) {
            int l = idx >> 4, c = idx & 15;
            if (l < len) {
                float4 v = embv[s_items[l] * 16 + c];
                s16x4 bv = { f2bf(v.x), f2bf(v.y), f2bf(v.z), f2bf(v.w) };
                *(s16x4*)&s_seq[l * SEQ_PITCH + c * 4] = bv;
            }
        }
    }
    // ---- stage attention weights transposed, bf16 ----
    for (int idx = t; idx < 64 * 64; idx += 256) {   // w1T[n][k] = aw1[64+k][n]
        int k = idx >> 6, n = idx & 63;
        s_w1T[n * SEQ_PITCH + k] = f2bf(aw1[(64 + k) * 64 + n]);
    }
    for (int idx = t; idx < 64 * 32; idx += 256) {   // w2T[n][k] = aw2[k][n]
        int k = idx >> 5, n = idx & 31;
        s_w2T[n * SEQ_PITCH + k] = f2bf(aw2[k * 32 + n]);
    }
    // ---- qc[j] = ab1[j] + tgt . aw1[0:64, j]  (fp32, once per block) ----
    if (t < 64) {
        float acc = ab1[t];
        for (int d = 0; d < 64; ++d) acc += s_comb[64 + d] * aw1[d * 64 + t];
        s_qc[t] = acc;
    }
    // ---- ctx hidden -> comb[128..159] ----
    if (t >= 64 && t < 96) {
        int j = t - 64;
        float acc = cb[j];
        for (int k = 0; k < 9; ++k) acc += ctx_feat[b * 9 + k] * cw[k * 32 + j];
        s_comb[128 + j] = fmaxf(acc, 0.f);
    }
    __syncthreads();   // B

    // ---- attention MLP via MFMA, one 16-row chunk per wave-iteration ----
    const float bias2_lo = ab2[r16],      bias2_hi = ab2[16 + r16];
    const float w3_lo    = aw3[r16],      w3_hi    = aw3[16 + r16];
    const float b3       = ab3[0];
    const float qcv0 = s_qc[r16],      qcv1 = s_qc[16 + r16];
    const float qcv2 = s_qc[32 + r16], qcv3 = s_qc[48 + r16];
    short* h1w = &s_h1[wave * 16 * SEQ_PITCH];

    for (int c = wave; c < 13; c += 4) {
        const int row0 = c * 16;
        // H1 = relu(seq_chunk @ aw1_seq + qc):  16x64, K=64
        f32x4 acc[4] = {{0,0,0,0},{0,0,0,0},{0,0,0,0},{0,0,0,0}};
        #pragma unroll
        for (int ks = 0; ks < 2; ++ks) {
            const int k0 = ks * 32;
            s16x8 a = *(const s16x8*)&s_seq[(row0 + r16) * SEQ_PITCH + k0 + quad * 8];
            #pragma unroll
            for (int nt = 0; nt < 4; ++nt) {
                s16x8 bf = *(const s16x8*)&s_w1T[(nt * 16 + r16) * SEQ_PITCH + k0 + quad * 8];
                acc[nt] = __builtin_amdgcn_mfma_f32_16x16x32_bf16(a, bf, acc[nt], 0, 0, 0);
            }
        }
        const float qcv[4] = {qcv0, qcv1, qcv2, qcv3};
        #pragma unroll
        for (int nt = 0; nt < 4; ++nt)
            #pragma unroll
            for (int r = 0; r < 4; ++r) {
                float v = fmaxf(acc[nt][r] + qcv[nt], 0.f);     // D: row=quad*4+r, col=nt*16+r16
                h1w[(quad * 4 + r) * SEQ_PITCH + nt * 16 + r16] = f2bf(v);
            }
        __builtin_amdgcn_wave_barrier();   // wave-local LDS RAW: DS is in-order per wave

        // H2 = relu(H1 @ aw2):  16x32, K=64 ; scores reduced in-register
        f32x4 acc2[2] = {{0,0,0,0},{0,0,0,0}};
        #pragma unroll
        for (int ks = 0; ks < 2; ++ks) {
            const int k0 = ks * 32;
            s16x8 a2 = *(const s16x8*)&h1w[r16 * SEQ_PITCH + k0 + quad * 8];
            #pragma unroll
            for (int nt = 0; nt < 2; ++nt) {
                s16x8 b2 = *(const s16x8*)&s_w2T[(nt * 16 + r16) * SEQ_PITCH + k0 + quad * 8];
                acc2[nt] = __builtin_amdgcn_mfma_f32_16x16x32_bf16(a2, b2, acc2[nt], 0, 0, 0);
            }
        }
        #pragma unroll
        for (int r = 0; r < 4; ++r) {
            float p = fmaxf(acc2[0][r] + bias2_lo, 0.f) * w3_lo
                    + fmaxf(acc2[1][r] + bias2_hi, 0.f) * w3_hi;
            p += __shfl_xor(p, 8);
            p += __shfl_xor(p, 4);
            p += __shfl_xor(p, 2);
            p += __shfl_xor(p, 1);
            if (r16 == 0) s_scores[row0 + quad * 4 + r] = p + b3;
        }
        __builtin_amdgcn_wave_barrier();
    }
    __syncthreads();   // C

    // ---- masked softmax over l < len (wave 0) ----
    if (t < 64) {
        float m = -1e30f;
        for (int l = t; l < len; l += 64) m = fmaxf(m, s_scores[l]);
        #pragma unroll
        for (int off = 32; off; off >>= 1) m = fmaxf(m, __shfl_xor(m, off));
        float e = 0.f;
        for (int l = t; l < len; l += 64) {
            float v = __expf(s_scores[l] - m);
            s_scores[l] = v;
            e += v;
        }
        #pragma unroll
        for (int off = 32; off; off >>= 1) e += __shfl_xor(e, off);
        if (t == 0) s_red = 1.f / e;
    }
    __syncthreads();   // D

    // ---- attended[d] = (1/Z) sum_l exp_l * seq[l][d] ----
    {
        const float inv = s_red;
        float acc = 0.f;
        for (int l = wave; l < len; l += 4)
            acc += s_scores[l] * bf2f(s_seq[l * SEQ_PITCH + lane]);
        s_part[wave * 64 + lane] = acc * inv;
    }
    __syncthreads();   // E
    if (t < 64)
        s_comb[t] = (s_part[t] + s_part[64 + t]) + (s_part[128 + t] + s_part[192 + t]);
    __syncthreads();   // F

    // ---- final MLP: 160 -> 128 (split-K over 2 halves) ----
    {
        const int col = t & 127, half = t >> 7;
        float acc = 0.f;
        #pragma unroll 4
        for (int k = half * 80; k < half * 80 + 80; ++k)
            acc += s_comb[k] * mw1[k * 128 + col];
        s_part[half * 128 + col] = acc;
    }
    __syncthreads();   // G
    if (t < 128) s_hm1[t] = fmaxf(s_part[t] + s_part[128 + t] + mb1[t], 0.f);
    __syncthreads();   // H

    // ---- 128 -> 64 (split-K over 4 quarters) -> 1, sigmoid ----
    {
        const int col = t & 63, q = t >> 6;
        float acc = 0.f;
        #pragma unroll 4
        for (int k = q * 32; k < q * 32 + 32; ++k)
            acc += s_hm1[k] * mw2[k * 64 + col];
        s_part[t] = acc;
    }
    __syncthreads();   // I
    if (t < 64) {
        float h = fmaxf(s_part[t] + s_part[64 + t] + s_part[128 + t] + s_part[192 + t] + mb2[t], 0.f);
        float p = h * mw3[t];
        #pragma unroll
        for (int off = 32; off; off >>= 1) p += __shfl_xor(p, off);
        if (t == 0) out[b] = 1.f / (1.f + __expf(-(p + mb3[0])));
    }
}

extern "C" void kernel_launch(void* const* d_in, const int* in_sizes, int n_in,
                              void* d_out, int out_size, void* d_ws, size_t ws_size,
                              hipStream_t stream)
{
    const int*   item_seq  = (const int*)  d_in[0];
    // d_in[1] click_sequence: unused by the reference
    const int*   seq_len   = (const int*)  d_in[2];
    const int*   tgt_item  = (const int*)  d_in[3];
    const float* ctx_feat  = (const float*)d_in[4];
    const float* emb       = (const float*)d_in[5];
    const float* aw1 = (const float*)d_in[6];
    const float* ab1 = (const float*)d_in[7];
    const float* aw2 = (const float*)d_in[8];
    const float* ab2 = (const float*)d_in[9];
    const float* aw3 = (const float*)d_in[10];
    const float* ab3 = (const float*)d_in[11];
    const float* cw  = (const float*)d_in[12];
    const float* cb  = (const float*)d_in[13];
    const float* mw1 = (const float*)d_in[14];
    const float* mb1 = (const float*)d_in[15];
    const float* mw2 = (const float*)d_in[16];
    const float* mb2 = (const float*)d_in[17];
    const float* mw3 = (const float*)d_in[18];
    const float* mb3 = (const float*)d_in[19];
    float* out = (float*)d_out;

    hipLaunchKernelGGL(din_fused_kernel, dim3(BB), dim3(256), 0, stream,
                       item_seq, seq_len, tgt_item, ctx_feat, emb,
                       aw1, ab1, aw2, ab2, aw3, ab3, cw, cb,
                       mw1, mb1, mw2, mb2, mw3, mb3, out);
}

// Round 3
// 286.083 us; speedup vs baseline: 3.3605x; 1.3933x over previous
//
#include <hip/hip_runtime.h>
#include <cmath>

#define BB 8192

typedef __attribute__((ext_vector_type(8))) short s16x8;   // 8 bf16 = 4 VGPRs (MFMA A/B frag)
typedef __attribute__((ext_vector_type(4))) short s16x4;
typedef __attribute__((ext_vector_type(4))) float f32x4;   // MFMA C/D frag

__device__ __forceinline__ short f2bf(float f) {
    union { float f; unsigned u; } v; v.f = f;
    unsigned r = v.u + 0x7FFFu + ((v.u >> 16) & 1u);   // RNE
    return (short)(r >> 16);
}
__device__ __forceinline__ float bf2f(short s) {
    union { unsigned u; float f; } v; v.u = ((unsigned)(unsigned short)s) << 16;
    return v.f;
}

// d_ws layout (shorts): [emb_bf16: 100001*64][w1T 64x64][w2T 32x64]
#define EMB_ELEMS 6400064
#define W1OFF EMB_ELEMS
#define W2OFF (EMB_ELEMS + 4096)
// ws bytes needed: (6400064+4096+2048)*2 = 12,812,416

__global__ __launch_bounds__(256)
void din_prep_kernel(const float* __restrict__ emb,
                     const float* __restrict__ aw1,
                     const float* __restrict__ aw2,
                     short* __restrict__ ws)
{
    if (blockIdx.x < 6251) {
        long e4 = ((long)blockIdx.x * 256 + threadIdx.x) * 4;
        if (e4 < EMB_ELEMS) {
            float4 v = *(const float4*)(emb + e4);
            s16x4 bv = { f2bf(v.x), f2bf(v.y), f2bf(v.z), f2bf(v.w) };
            *(s16x4*)(ws + e4) = bv;
        }
    } else {
        const int t = threadIdx.x;
        for (int idx = t; idx < 4096; idx += 256) {       // w1T[n][k] = aw1[64+k][n]
            int k = idx >> 6, n = idx & 63;
            ws[W1OFF + n * 64 + k] = f2bf(aw1[(64 + k) * 64 + n]);
        }
        for (int idx = t; idx < 2048; idx += 256) {       // w2T[n][k] = aw2[k][n]
            int k = idx >> 5, n = idx & 31;
            ws[W2OFF + n * 64 + k] = f2bf(aw2[k * 32 + n]);
        }
    }
}

#define H1_PITCH 72   // shorts; 144 B row stride keeps 16-B alignment, 2-way banks

__global__ __launch_bounds__(256, 4)
void din_fused_kernel(const int* __restrict__ item_seq,
                      const int* __restrict__ seq_len_p,
                      const int* __restrict__ tgt_item,
                      const float* __restrict__ ctx_feat,
                      const float* __restrict__ emb,
                      const float* __restrict__ aw1, const float* __restrict__ ab1,
                      const float* __restrict__ ab2,
                      const float* __restrict__ aw3, const float* __restrict__ ab3,
                      const float* __restrict__ cw,  const float* __restrict__ cb,
                      const float* __restrict__ mw1, const float* __restrict__ mb1,
                      const float* __restrict__ mw2, const float* __restrict__ mb2,
                      const float* __restrict__ mw3, const float* __restrict__ mb3,
                      const short* __restrict__ ws,
                      float* __restrict__ out)
{
    const int b    = blockIdx.x;
    const int t    = threadIdx.x;
    const int lane = t & 63;
    const int wave = t >> 6;
    const int quad = lane >> 4;   // 0..3
    const int r16  = lane & 15;   // 0..15

    __shared__ short s_h1[4 * 16 * H1_PITCH];   // 9,216 B per-wave H1 chunk
    __shared__ float s_scores[208];
    __shared__ int   s_items[200];
    __shared__ float s_comb[160];               // [attended | tgt | ctx]
    __shared__ float s_part[256];
    __shared__ float s_qc[64];
    __shared__ float s_hm1[128];
    __shared__ float s_red;

    const short* embbf = ws;
    const short* w1f   = ws + W1OFF;
    const short* w2f   = ws + W2OFF;

    const int tgt = tgt_item[b];
    const int len = seq_len_p[b];

    if (t < 200)             s_items[t] = item_seq[b * 200 + t];
    if (t >= 64 && t < 128)  s_comb[t]  = emb[tgt * 64 + (t - 64)];
    __syncthreads();   // A

    // ---- qc[j] = ab1[j] + tgt . aw1[0:64, j]  (fp32, once per block) ----
    if (t < 64) {
        float acc = ab1[t];
        for (int d = 0; d < 64; ++d) acc += s_comb[64 + d] * aw1[d * 64 + t];
        s_qc[t] = acc;
    }
    // ---- ctx hidden -> comb[128..159] ----
    if (t >= 64 && t < 96) {
        int j = t - 64;
        float acc = cb[j];
        for (int k = 0; k < 9; ++k) acc += ctx_feat[b * 9 + k] * cw[k * 32 + j];
        s_comb[128 + j] = fmaxf(acc, 0.f);
    }

    // ---- persistent weight fragments (48 VGPRs) ----
    s16x8 w1r[2][4], w2r[2][2];
    #pragma unroll
    for (int ks = 0; ks < 2; ++ks) {
        #pragma unroll
        for (int nt = 0; nt < 4; ++nt)
            w1r[ks][nt] = *(const s16x8*)(w1f + (nt * 16 + r16) * 64 + ks * 32 + quad * 8);
        #pragma unroll
        for (int nt = 0; nt < 2; ++nt)
            w2r[ks][nt] = *(const s16x8*)(w2f + (nt * 16 + r16) * 64 + ks * 32 + quad * 8);
    }
    const float bias2_lo = ab2[r16],  bias2_hi = ab2[16 + r16];
    const float w3_lo    = aw3[r16],  w3_hi    = aw3[16 + r16];
    const float b3       = ab3[0];
    __syncthreads();   // B  (qc ready)
    const float qcv[4] = { s_qc[r16], s_qc[16 + r16], s_qc[32 + r16], s_qc[48 + r16] };
    short* h1w = &s_h1[wave * 16 * H1_PITCH];

    // ---- attention MLP via MFMA; only chunks with live rows (len-gated) ----
    for (int c = wave; c * 16 < len; c += 4) {
        const int row0 = c * 16;
        int r = row0 + r16; if (r > 199) r = 199;
        const short* rp = embbf + s_items[r] * 64 + quad * 8;
        s16x8 a0 = *(const s16x8*)(rp);
        s16x8 a1 = *(const s16x8*)(rp + 32);

        // H1 = relu(seq_chunk @ aw1_seq + qc):  16x64, K=64
        f32x4 acc[4] = {{0,0,0,0},{0,0,0,0},{0,0,0,0},{0,0,0,0}};
        #pragma unroll
        for (int nt = 0; nt < 4; ++nt)
            acc[nt] = __builtin_amdgcn_mfma_f32_16x16x32_bf16(a0, w1r[0][nt], acc[nt], 0, 0, 0);
        #pragma unroll
        for (int nt = 0; nt < 4; ++nt)
            acc[nt] = __builtin_amdgcn_mfma_f32_16x16x32_bf16(a1, w1r[1][nt], acc[nt], 0, 0, 0);
        #pragma unroll
        for (int nt = 0; nt < 4; ++nt)
            #pragma unroll
            for (int rr = 0; rr < 4; ++rr) {
                float v = fmaxf(acc[nt][rr] + qcv[nt], 0.f);   // D: row=quad*4+rr, col=nt*16+r16
                h1w[(quad * 4 + rr) * H1_PITCH + nt * 16 + r16] = f2bf(v);
            }
        __builtin_amdgcn_wave_barrier();   // wave-local LDS RAW

        // H2 = relu(H1 @ aw2):  16x32, K=64; scores reduced in-register
        s16x8 h0 = *(const s16x8*)&h1w[r16 * H1_PITCH + quad * 8];
        s16x8 h1 = *(const s16x8*)&h1w[r16 * H1_PITCH + 32 + quad * 8];
        f32x4 acc2[2] = {{0,0,0,0},{0,0,0,0}};
        #pragma unroll
        for (int nt = 0; nt < 2; ++nt) {
            acc2[nt] = __builtin_amdgcn_mfma_f32_16x16x32_bf16(h0, w2r[0][nt], acc2[nt], 0, 0, 0);
            acc2[nt] = __builtin_amdgcn_mfma_f32_16x16x32_bf16(h1, w2r[1][nt], acc2[nt], 0, 0, 0);
        }
        #pragma unroll
        for (int rr = 0; rr < 4; ++rr) {
            float p = fmaxf(acc2[0][rr] + bias2_lo, 0.f) * w3_lo
                    + fmaxf(acc2[1][rr] + bias2_hi, 0.f) * w3_hi;
            p += __shfl_xor(p, 8);
            p += __shfl_xor(p, 4);
            p += __shfl_xor(p, 2);
            p += __shfl_xor(p, 1);
            if (r16 == 0) s_scores[row0 + quad * 4 + rr] = p + b3;
        }
        __builtin_amdgcn_wave_barrier();
    }
    __syncthreads();   // C

    // ---- masked softmax over l < len (wave 0) ----
    if (t < 64) {
        float m = -1e30f;
        for (int l = t; l < len; l += 64) m = fmaxf(m, s_scores[l]);
        #pragma unroll
        for (int off = 32; off; off >>= 1) m = fmaxf(m, __shfl_xor(m, off));
        float e = 0.f;
        for (int l = t; l < len; l += 64) {
            float v = __expf(s_scores[l] - m);
            s_scores[l] = v;
            e += v;
        }
        #pragma unroll
        for (int off = 32; off; off >>= 1) e += __shfl_xor(e, off);
        if (t == 0) s_red = 1.f / e;
    }
    __syncthreads();   // D

    // ---- attended[d] = (1/Z) sum_l exp_l * seq[l][d]  (bf16 rows from ws, coalesced) ----
    {
        const float inv = s_red;
        float acc = 0.f;
        for (int l = wave; l < len; l += 4)
            acc += s_scores[l] * bf2f(embbf[s_items[l] * 64 + lane]);
        s_part[wave * 64 + lane] = acc * inv;
    }
    __syncthreads();   // E
    if (t < 64)
        s_comb[t] = (s_part[t] + s_part[64 + t]) + (s_part[128 + t] + s_part[192 + t]);
    __syncthreads();   // F

    // ---- final MLP: 160 -> 128 (split-K over 2 halves) ----
    {
        const int col = t & 127, half = t >> 7;
        float acc = 0.f;
        #pragma unroll 4
        for (int k = half * 80; k < half * 80 + 80; ++k)
            acc += s_comb[k] * mw1[k * 128 + col];
        s_part[half * 128 + col] = acc;
    }
    __syncthreads();   // G
    if (t < 128) s_hm1[t] = fmaxf(s_part[t] + s_part[128 + t] + mb1[t], 0.f);
    __syncthreads();   // H

    // ---- 128 -> 64 (split-K over 4 quarters) -> 1, sigmoid ----
    {
        const int col = t & 63, q = t >> 6;
        float acc = 0.f;
        #pragma unroll 4
        for (int k = q * 32; k < q * 32 + 32; ++k)
            acc += s_hm1[k] * mw2[k * 64 + col];
        s_part[t] = acc;
    }
    __syncthreads();   // I
    if (t < 64) {
        float h = fmaxf(s_part[t] + s_part[64 + t] + s_part[128 + t] + s_part[192 + t] + mb2[t], 0.f);
        float p = h * mw3[t];
        #pragma unroll
        for (int off = 32; off; off >>= 1) p += __shfl_xor(p, off);
        if (t == 0) out[b] = 1.f / (1.f + __expf(-(p + mb3[0])));
    }
}

extern "C" void kernel_launch(void* const* d_in, const int* in_sizes, int n_in,
                              void* d_out, int out_size, void* d_ws, size_t ws_size,
                              hipStream_t stream)
{
    const int*   item_seq  = (const int*)  d_in[0];
    // d_in[1] click_sequence: unused by the reference
    const int*   seq_len   = (const int*)  d_in[2];
    const int*   tgt_item  = (const int*)  d_in[3];
    const float* ctx_feat  = (const float*)d_in[4];
    const float* emb       = (const float*)d_in[5];
    const float* aw1 = (const float*)d_in[6];
    const float* ab1 = (const float*)d_in[7];
    const float* aw2 = (const float*)d_in[8];
    const float* ab2 = (const float*)d_in[9];
    const float* aw3 = (const float*)d_in[10];
    const float* ab3 = (const float*)d_in[11];
    const float* cw  = (const float*)d_in[12];
    const float* cb  = (const float*)d_in[13];
    const float* mw1 = (const float*)d_in[14];
    const float* mb1 = (const float*)d_in[15];
    const float* mw2 = (const float*)d_in[16];
    const float* mb2 = (const float*)d_in[17];
    const float* mw3 = (const float*)d_in[18];
    const float* mb3 = (const float*)d_in[19];
    float* out = (float*)d_out;
    short* ws  = (short*)d_ws;

    hipLaunchKernelGGL(din_prep_kernel, dim3(6252), dim3(256), 0, stream,
                       emb, aw1, aw2, ws);
    hipLaunchKernelGGL(din_fused_kernel, dim3(BB), dim3(256), 0, stream,
                       item_seq, seq_len, tgt_item, ctx_feat, emb,
                       aw1, ab1, ab2, aw3, ab3, cw, cb,
                       mw1, mb1, mw2, mb2, mw3, mb3, ws, out);
}